// Round 3
// baseline (2128.329 us; speedup 1.0000x reference)
//
#include <hip/hip_runtime.h>
#include <hip/hip_bf16.h>

#define N_NODES 50000
#define N_EDGES 800000
#define F_INN   768
#define HID     128
#define N_CLS   9
#define ETOT    (N_EDGES + N_NODES)
#define BN_EPS  1e-5f

typedef __hip_bfloat16 bf16;

__device__ __forceinline__ float b2f(bf16 v) { return __bfloat162float(v); }
__device__ __forceinline__ float leaky(float v, float s) { return v >= 0.0f ? v : s * v; }
__device__ __forceinline__ int clampn(int s) {
  return ((unsigned)s < (unsigned)N_NODES) ? s : 0;
}
__device__ __forceinline__ float ldsel(const void* p, int i, int f32) {
  return f32 ? ((const float*)p)[i] : b2f(((const bf16*)p)[i]);
}

// converted-params (fp32) offsets inside P
#define OFF_W0   0
#define OFF_A0S  98304
#define OFF_A0D  98432
#define OFF_B0   98560
#define OFF_WM   98688
#define OFF_AMS  147840
#define OFF_AMD  148224
#define OFF_BM   148608
#define OFF_W4   148992
#define OFF_A4S  150144
#define OFF_A4D  150153
#define OFF_B4   150162
#define OFF_G    150171
#define OFF_BETA 150683
#define TOTALP   151195

// ---------------- dtype detection ----------------
// Read x's first 8192 elements AS bf16. True bf16 N(0,1): 0 huge/NaN values.
// fp32 bits read as bf16: low-half words are ~uniform random -> ~20% have
// |v|>1e10 or NaN. Threshold 100 cleanly separates.
__global__ void k_detect(const void* x, int* flag) {
  __shared__ int cnt_sh;
  if (threadIdx.x == 0) cnt_sh = 0;
  __syncthreads();
  int c = 0;
  for (int i = threadIdx.x; i < 8192; i += 256) {
    float v = b2f(((const bf16*)x)[i]);
    if (!(fabsf(v) < 1e10f)) c++;  // catches NaN too
  }
  atomicAdd(&cnt_sh, c);
  __syncthreads();
  if (threadIdx.x == 0) flag[0] = (cnt_sh > 100) ? 1 : 0;
}

// ---------------- convert all params to fp32 into P ----------------
__global__ void k_cvt(const int* __restrict__ flag, float* __restrict__ P,
                      const void* W0, const void* a0s, const void* a0d, const void* b0,
                      const void* Wm, const void* ams, const void* amd, const void* bm,
                      const void* W4, const void* a4s, const void* a4d, const void* b4,
                      const void* g, const void* be) {
  int f32 = flag[0];
  int i = blockIdx.x * blockDim.x + threadIdx.x;
  if (i >= TOTALP) return;
  const void* src;
  int j;
  if      (i < OFF_A0S)  { src = W0;  j = i - OFF_W0; }
  else if (i < OFF_A0D)  { src = a0s; j = i - OFF_A0S; }
  else if (i < OFF_B0)   { src = a0d; j = i - OFF_A0D; }
  else if (i < OFF_WM)   { src = b0;  j = i - OFF_B0; }
  else if (i < OFF_AMS)  { src = Wm;  j = i - OFF_WM; }
  else if (i < OFF_AMD)  { src = ams; j = i - OFF_AMS; }
  else if (i < OFF_BM)   { src = amd; j = i - OFF_AMD; }
  else if (i < OFF_W4)   { src = bm;  j = i - OFF_BM; }
  else if (i < OFF_A4S)  { src = W4;  j = i - OFF_W4; }
  else if (i < OFF_A4D)  { src = a4s; j = i - OFF_A4S; }
  else if (i < OFF_B4)   { src = a4d; j = i - OFF_A4D; }
  else if (i < OFF_G)    { src = b4;  j = i - OFF_B4; }
  else if (i < OFF_BETA) { src = g;   j = i - OFF_G; }
  else                   { src = be;  j = i - OFF_BETA; }
  P[i] = ldsel(src, j, f32);
}

// ---------------- utility: zero a small fp32 region ----------------
__global__ void k_zero(float* p, int n) {
  int i = blockIdx.x * blockDim.x + threadIdx.x;
  if (i < n) p[i] = 0.0f;
}

// ---------------- CSR build ----------------
__global__ void k_init_deg(int* fill) {
  int i = blockIdx.x * blockDim.x + threadIdx.x;
  if (i < N_NODES) fill[i] = 1;  // self-loop
}

__global__ void k_count(const int* __restrict__ dst, int* fill) {
  int e = blockIdx.x * blockDim.x + threadIdx.x;
  if (e < N_EDGES) atomicAdd(&fill[clampn(dst[e])], 1);
}

__global__ void k_scan(int* fill, int* row_ptr) {
  __shared__ int sh[1024];
  int tid = threadIdx.x;
  int carry = 0;
  for (int base = 0; base < N_NODES; base += 1024) {
    int i = base + tid;
    int v = (i < N_NODES) ? fill[i] : 0;
    if (i < N_NODES) fill[i] = 0;
    sh[tid] = v;
    __syncthreads();
    for (int off = 1; off < 1024; off <<= 1) {
      int t = (tid >= off) ? sh[tid - off] : 0;
      __syncthreads();
      sh[tid] += t;
      __syncthreads();
    }
    if (i < N_NODES) row_ptr[i] = carry + sh[tid] - v;
    int tot = sh[1023];
    __syncthreads();
    carry += tot;
  }
  if (tid == 0) row_ptr[N_NODES] = carry;
}

__global__ void k_place(const int* __restrict__ src, const int* __restrict__ dst,
                        const int* __restrict__ row_ptr, int* fill, int* csr_src) {
  int id = blockIdx.x * blockDim.x + threadIdx.x;
  if (id >= ETOT) return;
  int s, d;
  if (id < N_EDGES) { s = clampn(src[id]); d = clampn(dst[id]); }
  else { s = id - N_EDGES; d = s; }
  int p = atomicAdd(&fill[d], 1);
  csr_src[row_ptr[d] + p] = s;
}

// ---------------- layer-0 GEMM: out[N,128] = x[N,768] @ W0[768,128] ----------------
__global__ void k_gemm0(const void* __restrict__ A, const float* __restrict__ W,
                        const int* __restrict__ flag, float* __restrict__ out) {
  int f32 = flag[0];
  __shared__ float xs[8][F_INN];
  int f = threadIdx.x;  // 0..127
  int row0 = blockIdx.x * 8;
  for (int idx = f; idx < 8 * F_INN; idx += 128)
    xs[idx / F_INN][idx % F_INN] = ldsel(A, row0 * F_INN + idx, f32);
  __syncthreads();
  float acc[8];
#pragma unroll
  for (int r = 0; r < 8; ++r) acc[r] = 0.0f;
  for (int k = 0; k < F_INN; ++k) {
    float w = W[k * HID + f];
#pragma unroll
    for (int r = 0; r < 8; ++r) acc[r] += xs[r][k] * w;
  }
#pragma unroll
  for (int r = 0; r < 8; ++r) out[(row0 + r) * HID + f] = acc[r];
}

// ---------------- mid GEMM with fused BN+leaky0.1 on input ----------------
__global__ void k_gemm_mid(const float* __restrict__ h, const float* __restrict__ W,
                           const float* __restrict__ scale, const float* __restrict__ shift,
                           float* __restrict__ out) {
  __shared__ float xs[8][HID];
  int f = threadIdx.x;
  int row0 = blockIdx.x * 8;
  float sc = scale[f], sf = shift[f];
#pragma unroll
  for (int r = 0; r < 8; ++r)
    xs[r][f] = leaky(h[(row0 + r) * HID + f] * sc + sf, 0.1f);
  __syncthreads();
  float acc[8];
#pragma unroll
  for (int r = 0; r < 8; ++r) acc[r] = 0.0f;
  for (int k = 0; k < HID; ++k) {
    float w = W[k * HID + f];
#pragma unroll
    for (int r = 0; r < 8; ++r) acc[r] += xs[r][k] * w;
  }
#pragma unroll
  for (int r = 0; r < 8; ++r) out[(row0 + r) * HID + f] = acc[r];
}

// ---------------- per-node attention logits ----------------
__global__ void k_alphas(const float* __restrict__ h, const float* __restrict__ a_s,
                         const float* __restrict__ a_d, float* __restrict__ asrc,
                         float* __restrict__ adst) {
  int wid = (blockIdx.x * blockDim.x + threadIdx.x) >> 6;
  int lane = threadIdx.x & 63;
  if (wid >= N_NODES) return;
  float v0 = h[wid * HID + lane];
  float v1 = h[wid * HID + 64 + lane];
  float s = v0 * a_s[lane] + v1 * a_s[lane + 64];
  float d = v0 * a_d[lane] + v1 * a_d[lane + 64];
#pragma unroll
  for (int m = 32; m; m >>= 1) {
    s += __shfl_xor(s, m);
    d += __shfl_xor(d, m);
  }
  if (lane == 0) { asrc[wid] = s; adst[wid] = d; }
}

// ---------------- GAT aggregation (H=128): one wave per node ----------------
__global__ void k_agg128(const float* __restrict__ h, const float* __restrict__ asrc,
                         const float* __restrict__ adst, const int* __restrict__ row_ptr,
                         const int* __restrict__ csr_src, const float* __restrict__ bias,
                         const float* __restrict__ hres, const float* __restrict__ scale,
                         const float* __restrict__ shift, float* __restrict__ out) {
  int wid = (blockIdx.x * blockDim.x + threadIdx.x) >> 6;
  int lane = threadIdx.x & 63;
  if (wid >= N_NODES) return;
  int beg = row_ptr[wid], end = row_ptr[wid + 1];
  float adsti = adst[wid];
  float m = -1e30f;
  for (int e = beg; e < end; ++e) {
    int s = clampn(csr_src[e]);
    float v = leaky(asrc[s] + adsti, 0.2f);
    m = fmaxf(m, v);
  }
  float z = 0.0f, a0 = 0.0f, a1 = 0.0f;
  for (int e = beg; e < end; ++e) {
    int s = clampn(csr_src[e]);
    float v = leaky(asrc[s] + adsti, 0.2f);
    float ex = __expf(v - m);
    z += ex;
    a0 += ex * h[s * HID + lane];
    a1 += ex * h[s * HID + 64 + lane];
  }
  float inv = (z > 0.0f) ? 1.0f / z : 0.0f;
  float o0 = a0 * inv + bias[lane];
  float o1 = a1 * inv + bias[64 + lane];
  if (scale) {
    o0 += leaky(hres[wid * HID + lane] * scale[lane] + shift[lane], 0.1f);
    o1 += leaky(hres[wid * HID + 64 + lane] * scale[64 + lane] + shift[64 + lane], 0.1f);
  }
  out[wid * HID + lane] = o0;
  out[wid * HID + 64 + lane] = o1;
}

// ---------------- BatchNorm stats ----------------
__global__ void k_bn_stats(const float* __restrict__ h, float* bnsum, float* bnsumsq) {
  int f = threadIdx.x;  // 128
  int r0 = blockIdx.x * 512;
  int r1 = min(r0 + 512, N_NODES);
  float s = 0.0f, s2 = 0.0f;
  for (int r = r0; r < r1; ++r) {
    float v = h[r * HID + f];
    s += v;
    s2 += v * v;
  }
  atomicAdd(&bnsum[f], s);
  atomicAdd(&bnsumsq[f], s2);
}

__global__ void k_bn_final(const float* __restrict__ bnsum, const float* __restrict__ bnsumsq,
                           const float* __restrict__ gamma, const float* __restrict__ beta,
                           float* bnscale, float* bnshift) {
  int f = threadIdx.x;
  float mu = bnsum[f] / (float)N_NODES;
  float var = bnsumsq[f] / (float)N_NODES - mu * mu;
  var = fmaxf(var, 0.0f);
  float rstd = rsqrtf(var + BN_EPS);
  float g = gamma[f];
  bnscale[f] = g * rstd;
  bnshift[f] = beta[f] - mu * g * rstd;
}

// ---------------- final layer GEMM (BN fused) + alpha logits ----------------
__global__ void k_final_gemm(const float* __restrict__ h, const float* __restrict__ scale,
                             const float* __restrict__ shift, const float* __restrict__ W4,
                             const float* __restrict__ a4s, const float* __restrict__ a4d,
                             float* __restrict__ h4, float* __restrict__ asrc,
                             float* __restrict__ adst) {
  int row = (blockIdx.x * blockDim.x + threadIdx.x) >> 6;
  int lane = threadIdx.x & 63;
  if (row >= N_NODES) return;
  float t0 = leaky(h[row * HID + lane] * scale[lane] + shift[lane], 0.1f);
  float t1 = leaky(h[row * HID + 64 + lane] * scale[64 + lane] + shift[64 + lane], 0.1f);
  float myv = 0.0f, s = 0.0f, d = 0.0f;
#pragma unroll
  for (int c = 0; c < N_CLS; ++c) {
    float p = t0 * W4[lane * N_CLS + c] + t1 * W4[(lane + 64) * N_CLS + c];
#pragma unroll
    for (int m = 32; m; m >>= 1) p += __shfl_xor(p, m);
    s += p * a4s[c];
    d += p * a4d[c];
    if (lane == c) myv = p;
  }
  if (lane < N_CLS) h4[row * N_CLS + lane] = myv;
  if (lane == 0) { asrc[row] = s; adst[row] = d; }
}

// ---------------- final aggregation (C=9) -> output (dtype per flag) ----------------
__global__ void k_final_agg(const float* __restrict__ h4, const float* __restrict__ asrc,
                            const float* __restrict__ adst, const int* __restrict__ row_ptr,
                            const int* __restrict__ csr_src, const float* __restrict__ b4,
                            const int* __restrict__ flag, void* __restrict__ outv) {
  int wid = (blockIdx.x * blockDim.x + threadIdx.x) >> 6;
  int lane = threadIdx.x & 63;
  if (wid >= N_NODES) return;
  int f32 = flag[0];
  int beg = row_ptr[wid], end = row_ptr[wid + 1];
  float adsti = adst[wid];
  float m = -1e30f;
  for (int e = beg; e < end; ++e) {
    int s = clampn(csr_src[e]);
    float v = leaky(asrc[s] + adsti, 0.2f);
    m = fmaxf(m, v);
  }
  float z = 0.0f, a = 0.0f;
  for (int e = beg; e < end; ++e) {
    int s = clampn(csr_src[e]);
    float v = leaky(asrc[s] + adsti, 0.2f);
    float ex = __expf(v - m);
    z += ex;
    if (lane < N_CLS) a += ex * h4[s * N_CLS + lane];
  }
  if (lane < N_CLS) {
    float o = (z > 0.0f) ? a / z : 0.0f;
    o = leaky(o + b4[lane], 0.1f);
    if (f32) ((float*)outv)[wid * N_CLS + lane] = o;
    else ((bf16*)outv)[wid * N_CLS + lane] = __float2bfloat16(o);
  }
}

extern "C" void kernel_launch(void* const* d_in, const int* in_sizes, int n_in,
                              void* d_out, int out_size, void* d_ws, size_t ws_size,
                              hipStream_t stream) {
  const void* x   = d_in[0];
  const int*  ei  = (const int*)d_in[1];
  const int*  src = ei;
  const int*  dst = ei + N_EDGES;

  // ---- workspace layout: flag + ints first, big fp32 buffers last (~58 MB) ----
  int* flag      = (int*)d_ws;                    // 1 (+3 pad)
  int* row_ptr   = flag + 4;                      // N+1
  int* fill      = row_ptr + N_NODES + 1;         // N
  int* csr_src   = fill + N_NODES;                // ETOT
  float* P       = (float*)(csr_src + ETOT);      // TOTALP fp32 params
  float* asrc    = P + TOTALP;                    // N
  float* adst    = asrc + N_NODES;                // N
  float* bnsum   = adst + N_NODES;                // 128
  float* bnsumsq = bnsum + HID;                   // 128
  float* bnscale = bnsumsq + HID;                 // 128
  float* bnshift = bnscale + HID;                 // 128
  float* h4      = bnshift + HID;                 // N*9
  float* bufA    = h4 + N_NODES * N_CLS;          // N*128  (pre-agg h)
  float* bufB    = bufA + N_NODES * HID;          // N*128  (running h)

  const int B256 = 256;
  int gN   = (N_NODES + B256 - 1) / B256;
  int gE   = (N_EDGES + B256 - 1) / B256;
  int gET  = (ETOT + B256 - 1) / B256;
  int gWav = (N_NODES + 3) / 4;
  int gBN  = (N_NODES + 511) / 512;
  int gCvt = (TOTALP + B256 - 1) / B256;

  // ---- dtype detect + param conversion ----
  k_detect<<<1, B256, 0, stream>>>(x, flag);
  k_cvt<<<gCvt, B256, 0, stream>>>(flag, P,
      d_in[4], d_in[5], d_in[6], d_in[7], d_in[8], d_in[9], d_in[10], d_in[11],
      d_in[12], d_in[13], d_in[14], d_in[15], d_in[16], d_in[17]);

  // ---- CSR ----
  k_init_deg<<<gN, B256, 0, stream>>>(fill);
  k_count<<<gE, B256, 0, stream>>>(dst, fill);
  k_scan<<<1, 1024, 0, stream>>>(fill, row_ptr);
  k_place<<<gET, B256, 0, stream>>>(src, dst, row_ptr, fill, csr_src);

  // ---- layer 0 ----
  k_gemm0<<<N_NODES / 8, 128, 0, stream>>>(x, P + OFF_W0, flag, bufA);
  k_alphas<<<gWav, B256, 0, stream>>>(bufA, P + OFF_A0S, P + OFF_A0D, asrc, adst);
  k_agg128<<<gWav, B256, 0, stream>>>(bufA, asrc, adst, row_ptr, csr_src, P + OFF_B0,
                                      nullptr, nullptr, nullptr, bufB);

  // ---- mid layers ----
  for (int i = 0; i < 3; ++i) {
    k_zero<<<1, 256, 0, stream>>>(bnsum, 2 * HID);
    k_bn_stats<<<gBN, HID, 0, stream>>>(bufB, bnsum, bnsumsq);
    k_bn_final<<<1, HID, 0, stream>>>(bnsum, bnsumsq, P + OFF_G + i * HID,
                                      P + OFF_BETA + i * HID, bnscale, bnshift);
    k_gemm_mid<<<N_NODES / 8, 128, 0, stream>>>(bufB, P + OFF_WM + i * HID * HID,
                                                bnscale, bnshift, bufA);
    k_alphas<<<gWav, B256, 0, stream>>>(bufA, P + OFF_AMS + i * HID, P + OFF_AMD + i * HID,
                                        asrc, adst);
    k_agg128<<<gWav, B256, 0, stream>>>(bufA, asrc, adst, row_ptr, csr_src,
                                        P + OFF_BM + i * HID, bufB, bnscale, bnshift, bufB);
  }

  // ---- final ----
  k_zero<<<1, 256, 0, stream>>>(bnsum, 2 * HID);
  k_bn_stats<<<gBN, HID, 0, stream>>>(bufB, bnsum, bnsumsq);
  k_bn_final<<<1, HID, 0, stream>>>(bnsum, bnsumsq, P + OFF_G + 3 * HID,
                                    P + OFF_BETA + 3 * HID, bnscale, bnshift);
  k_final_gemm<<<gWav, B256, 0, stream>>>(bufB, bnscale, bnshift, P + OFF_W4,
                                          P + OFF_A4S, P + OFF_A4D, h4, asrc, adst);
  k_final_agg<<<gWav, B256, 0, stream>>>(h4, asrc, adst, row_ptr, csr_src, P + OFF_B4,
                                         flag, d_out);
}

// Round 4
// 1420.922 us; speedup vs baseline: 1.4979x; 1.4979x over previous
//
#include <hip/hip_runtime.h>
#include <hip/hip_bf16.h>

#define N_NODES 50000
#define N_EDGES 800000
#define F_INN   768
#define HID     128
#define N_CLS   9
#define ETOT    (N_EDGES + N_NODES)
#define BN_EPS  1e-5f

typedef __hip_bfloat16 bf16;
typedef __attribute__((ext_vector_type(8))) short bf16x8;
typedef __attribute__((ext_vector_type(4))) float f32x4;

__device__ __forceinline__ float leaky(float v, float s) { return v >= 0.0f ? v : s * v; }
__device__ __forceinline__ int clampn(int s) {
  return ((unsigned)s < (unsigned)N_NODES) ? s : 0;
}
__device__ __forceinline__ short f2bs(float f) {
  bf16 h = __float2bfloat16(f);
  return __builtin_bit_cast(short, h);
}
__device__ __forceinline__ float bs2f(unsigned short u) {
  unsigned v = ((unsigned)u) << 16;
  return __builtin_bit_cast(float, v);
}

// ---------------- pack W0^T, Wm^T to bf16 [n][k] ----------------
__global__ void k_pack(const float* __restrict__ W0, const float* __restrict__ Wm,
                       short* __restrict__ W0T, short* __restrict__ WmT) {
  int i = blockIdx.x * blockDim.x + threadIdx.x;
  if (i < F_INN * HID) {
    int n = i / F_INN, k = i % F_INN;          // W0T[n*768+k] = W0[k*128+n]
    W0T[i] = f2bs(W0[k * HID + n]);
  } else if (i < F_INN * HID + 3 * HID * HID) {
    int j = i - F_INN * HID;
    int l = j / (HID * HID), rem = j % (HID * HID);
    int n = rem / HID, k = rem % HID;          // WmT[l][n*128+k] = Wm[l][k*128+n]
    WmT[j] = f2bs(Wm[(l * HID + k) * HID + n]);
  }
}

// ---------------- utility: zero a small fp32 region ----------------
__global__ void k_zero(float* p, int n) {
  int i = blockIdx.x * blockDim.x + threadIdx.x;
  if (i < n) p[i] = 0.0f;
}

// ---------------- CSR build ----------------
__global__ void k_init_deg(int* fill) {
  int i = blockIdx.x * blockDim.x + threadIdx.x;
  if (i < N_NODES) fill[i] = 1;  // self-loop
}

__global__ void k_count(const int* __restrict__ dst, int* fill) {
  int e = blockIdx.x * blockDim.x + threadIdx.x;
  if (e < N_EDGES) atomicAdd(&fill[clampn(dst[e])], 1);
}

__global__ void k_scan(int* fill, int* row_ptr) {
  __shared__ int sh[1024];
  int tid = threadIdx.x;
  int carry = 0;
  for (int base = 0; base < N_NODES; base += 1024) {
    int i = base + tid;
    int v = (i < N_NODES) ? fill[i] : 0;
    if (i < N_NODES) fill[i] = 0;
    sh[tid] = v;
    __syncthreads();
    for (int off = 1; off < 1024; off <<= 1) {
      int t = (tid >= off) ? sh[tid - off] : 0;
      __syncthreads();
      sh[tid] += t;
      __syncthreads();
    }
    if (i < N_NODES) row_ptr[i] = carry + sh[tid] - v;
    int tot = sh[1023];
    __syncthreads();
    carry += tot;
  }
  if (tid == 0) row_ptr[N_NODES] = carry;
}

__global__ void k_place(const int* __restrict__ src, const int* __restrict__ dst,
                        const int* __restrict__ row_ptr, int* fill, int* csr_src) {
  int id = blockIdx.x * blockDim.x + threadIdx.x;
  if (id >= ETOT) return;
  int s, d;
  if (id < N_EDGES) { s = clampn(src[id]); d = clampn(dst[id]); }
  else { s = id - N_EDGES; d = s; }
  int p = atomicAdd(&fill[d], 1);
  csr_src[row_ptr[d] + p] = s;
}

// ---------------- MFMA GEMM: hb[N,128](bf16) = act(X[N,K]) @ BT^T ----------------
// One wave per 16 rows, all 128 cols (8 MFMA col-tiles of 16x16x32 bf16).
// A-frag: A[m=lane&15][k=q*8+j] loaded fp32->bf16 in-register.
// B-frag: BT[n=lane&15 + t*16][k=q*8+j] (BT row-major [128][K] bf16).
// C-frag: D[row=q*4+r][col=lane&15 + t*16]  (m89-verified layout).
// BN=true applies t=leaky(x*scale+shift,0.1) to A before the matmul.
// Epilogue fuses asrc/adst = h . a_s / a_d (16-lane shuffle reduce).
template <int K, bool BN>
__global__ void k_gemm_mfma(const float* __restrict__ X, const short* __restrict__ BT,
                            const float* __restrict__ scale, const float* __restrict__ shift,
                            const float* __restrict__ a_s, const float* __restrict__ a_d,
                            short* __restrict__ hb, float* __restrict__ asrc,
                            float* __restrict__ adst) {
  int wave = (blockIdx.x * blockDim.x + threadIdx.x) >> 6;
  if (wave >= N_NODES / 16) return;
  int lane = threadIdx.x & 63;
  int m = lane & 15, q = lane >> 4;
  int row0 = wave * 16;
  f32x4 acc[8];
#pragma unroll
  for (int t = 0; t < 8; ++t) acc[t] = (f32x4){0.f, 0.f, 0.f, 0.f};
  const float* xrow = X + (size_t)(row0 + m) * K + q * 8;
  const short* brow = BT + (size_t)m * K + q * 8;
  for (int kc = 0; kc < K; kc += 32) {
    float xv[8];
    *(float4*)(xv)     = *(const float4*)(xrow + kc);
    *(float4*)(xv + 4) = *(const float4*)(xrow + kc + 4);
    if (BN) {
      float sc[8], sf[8];
      *(float4*)(sc)     = *(const float4*)(scale + kc + q * 8);
      *(float4*)(sc + 4) = *(const float4*)(scale + kc + q * 8 + 4);
      *(float4*)(sf)     = *(const float4*)(shift + kc + q * 8);
      *(float4*)(sf + 4) = *(const float4*)(shift + kc + q * 8 + 4);
#pragma unroll
      for (int j = 0; j < 8; ++j) xv[j] = leaky(xv[j] * sc[j] + sf[j], 0.1f);
    }
    bf16x8 a;
#pragma unroll
    for (int j = 0; j < 8; ++j) a[j] = f2bs(xv[j]);
#pragma unroll
    for (int t = 0; t < 8; ++t) {
      bf16x8 b = *(const bf16x8*)(brow + kc + (size_t)t * 16 * K);
      acc[t] = __builtin_amdgcn_mfma_f32_16x16x32_bf16(a, b, acc[t], 0, 0, 0);
    }
  }
  // epilogue: store bf16 h, fused attention logits
  float sr[4] = {0.f, 0.f, 0.f, 0.f}, dr[4] = {0.f, 0.f, 0.f, 0.f};
#pragma unroll
  for (int t = 0; t < 8; ++t) {
    float av = a_s[t * 16 + m], dv = a_d[t * 16 + m];
#pragma unroll
    for (int r = 0; r < 4; ++r) {
      float c = acc[t][r];
      hb[(size_t)(row0 + q * 4 + r) * HID + t * 16 + m] = f2bs(c);
      sr[r] += c * av;
      dr[r] += c * dv;
    }
  }
#pragma unroll
  for (int r = 0; r < 4; ++r) {
#pragma unroll
    for (int off = 1; off < 16; off <<= 1) {
      sr[r] += __shfl_xor(sr[r], off);
      dr[r] += __shfl_xor(dr[r], off);
    }
  }
  if (m == 0) {
#pragma unroll
    for (int r = 0; r < 4; ++r) {
      asrc[row0 + q * 4 + r] = sr[r];
      adst[row0 + q * 4 + r] = dr[r];
    }
  }
}

// ---------------- GAT aggregation (H=128, bf16 h): one wave per node ----------------
// Lane handles col pair (2*lane, 2*lane+1): one 4B gather per edge per lane.
// If scale!=null adds residual t = leaky(hres*scale+shift, 0.1); hres may alias out
// (wave reads only its own row before writing it).
__global__ void k_agg128(const unsigned short* __restrict__ h, const float* __restrict__ asrc,
                         const float* __restrict__ adst, const int* __restrict__ row_ptr,
                         const int* __restrict__ csr_src, const float* __restrict__ bias,
                         const float* __restrict__ hres, const float* __restrict__ scale,
                         const float* __restrict__ shift, float* __restrict__ out) {
  int wid = (blockIdx.x * blockDim.x + threadIdx.x) >> 6;
  int lane = threadIdx.x & 63;
  if (wid >= N_NODES) return;
  int c0 = 2 * lane;
  int beg = row_ptr[wid], end = row_ptr[wid + 1];
  float adsti = adst[wid];
  float mx = -1e30f;
  for (int e = beg; e < end; ++e) {
    int s = clampn(csr_src[e]);
    float v = leaky(asrc[s] + adsti, 0.2f);
    mx = fmaxf(mx, v);
  }
  float z = 0.0f, a0 = 0.0f, a1 = 0.0f;
  for (int e = beg; e < end; ++e) {
    int s = clampn(csr_src[e]);
    float v = leaky(asrc[s] + adsti, 0.2f);
    float ex = __expf(v - mx);
    z += ex;
    unsigned hv = *(const unsigned*)(h + (size_t)s * HID + c0);
    a0 += ex * bs2f((unsigned short)(hv & 0xffffu));
    a1 += ex * bs2f((unsigned short)(hv >> 16));
  }
  float inv = (z > 0.0f) ? 1.0f / z : 0.0f;
  float o0 = a0 * inv + bias[c0];
  float o1 = a1 * inv + bias[c0 + 1];
  if (scale) {
    float2 hr = *(const float2*)(hres + (size_t)wid * HID + c0);
    o0 += leaky(hr.x * scale[c0] + shift[c0], 0.1f);
    o1 += leaky(hr.y * scale[c0 + 1] + shift[c0 + 1], 0.1f);
  }
  float2 o = {o0, o1};
  *(float2*)(out + (size_t)wid * HID + c0) = o;
}

// ---------------- BatchNorm stats ----------------
__global__ void k_bn_stats(const float* __restrict__ h, float* bnsum, float* bnsumsq) {
  int f = threadIdx.x;  // 128
  int r0 = blockIdx.x * 128;
  int r1 = min(r0 + 128, N_NODES);
  float s = 0.0f, s2 = 0.0f;
  for (int r = r0; r < r1; ++r) {
    float v = h[(size_t)r * HID + f];
    s += v;
    s2 += v * v;
  }
  atomicAdd(&bnsum[f], s);
  atomicAdd(&bnsumsq[f], s2);
}

__global__ void k_bn_final(const float* __restrict__ bnsum, const float* __restrict__ bnsumsq,
                           const float* __restrict__ gamma, const float* __restrict__ beta,
                           float* bnscale, float* bnshift) {
  int f = threadIdx.x;
  float mu = bnsum[f] / (float)N_NODES;
  float var = bnsumsq[f] / (float)N_NODES - mu * mu;
  var = fmaxf(var, 0.0f);
  float rstd = rsqrtf(var + BN_EPS);
  float g = gamma[f];
  bnscale[f] = g * rstd;
  bnshift[f] = beta[f] - mu * g * rstd;
}

// ---------------- final layer GEMM (BN fused) + alpha logits ----------------
__global__ void k_final_gemm(const float* __restrict__ h, const float* __restrict__ scale,
                             const float* __restrict__ shift, const float* __restrict__ W4,
                             const float* __restrict__ a4s, const float* __restrict__ a4d,
                             float* __restrict__ h4, float* __restrict__ asrc,
                             float* __restrict__ adst) {
  int row = (blockIdx.x * blockDim.x + threadIdx.x) >> 6;
  int lane = threadIdx.x & 63;
  if (row >= N_NODES) return;
  float t0 = leaky(h[(size_t)row * HID + lane] * scale[lane] + shift[lane], 0.1f);
  float t1 = leaky(h[(size_t)row * HID + 64 + lane] * scale[64 + lane] + shift[64 + lane], 0.1f);
  float myv = 0.0f, s = 0.0f, d = 0.0f;
#pragma unroll
  for (int c = 0; c < N_CLS; ++c) {
    float p = t0 * W4[lane * N_CLS + c] + t1 * W4[(lane + 64) * N_CLS + c];
#pragma unroll
    for (int m = 32; m; m >>= 1) p += __shfl_xor(p, m);
    s += p * a4s[c];
    d += p * a4d[c];
    if (lane == c) myv = p;
  }
  if (lane < N_CLS) h4[(size_t)row * N_CLS + lane] = myv;
  if (lane == 0) { asrc[row] = s; adst[row] = d; }
}

// ---------------- final aggregation (C=9) -> fp32 output ----------------
__global__ void k_final_agg(const float* __restrict__ h4, const float* __restrict__ asrc,
                            const float* __restrict__ adst, const int* __restrict__ row_ptr,
                            const int* __restrict__ csr_src, const float* __restrict__ b4,
                            float* __restrict__ out) {
  int wid = (blockIdx.x * blockDim.x + threadIdx.x) >> 6;
  int lane = threadIdx.x & 63;
  if (wid >= N_NODES) return;
  int beg = row_ptr[wid], end = row_ptr[wid + 1];
  float adsti = adst[wid];
  float mx = -1e30f;
  for (int e = beg; e < end; ++e) {
    int s = clampn(csr_src[e]);
    float v = leaky(asrc[s] + adsti, 0.2f);
    mx = fmaxf(mx, v);
  }
  float z = 0.0f, a = 0.0f;
  for (int e = beg; e < end; ++e) {
    int s = clampn(csr_src[e]);
    float v = leaky(asrc[s] + adsti, 0.2f);
    float ex = __expf(v - mx);
    z += ex;
    if (lane < N_CLS) a += ex * h4[(size_t)s * N_CLS + lane];
  }
  if (lane < N_CLS) {
    float o = (z > 0.0f) ? a / z : 0.0f;
    o = leaky(o + b4[lane], 0.1f);
    out[(size_t)wid * N_CLS + lane] = o;
  }
}

extern "C" void kernel_launch(void* const* d_in, const int* in_sizes, int n_in,
                              void* d_out, int out_size, void* d_ws, size_t ws_size,
                              hipStream_t stream) {
  const float* x   = (const float*)d_in[0];
  const int*   ei  = (const int*)d_in[1];
  const int*   src = ei;
  const int*   dst = ei + N_EDGES;
  const float* W0  = (const float*)d_in[4];
  const float* a0s = (const float*)d_in[5];
  const float* a0d = (const float*)d_in[6];
  const float* b0  = (const float*)d_in[7];
  const float* Wm  = (const float*)d_in[8];
  const float* ams = (const float*)d_in[9];
  const float* amd = (const float*)d_in[10];
  const float* bm  = (const float*)d_in[11];
  const float* W4  = (const float*)d_in[12];
  const float* a4s = (const float*)d_in[13];
  const float* a4d = (const float*)d_in[14];
  const float* b4  = (const float*)d_in[15];
  const float* gam = (const float*)d_in[16];
  const float* bet = (const float*)d_in[17];
  float* out = (float*)d_out;

  // ---- workspace layout (~45 MB): ints, then bf16 (16B-aligned), then fp32 ----
  int* row_ptr   = (int*)d_ws;                    // 50001 (padded to 50004)
  int* fill      = row_ptr + 50004;               // N
  int* csr_src   = fill + N_NODES;                // ETOT
  short* W0T     = (short*)(csr_src + ETOT);      // 98304  (offset 3800016 B, 16-aligned)
  short* WmT     = W0T + F_INN * HID;             // 49152
  short* bufA    = WmT + 3 * HID * HID;           // N*128 bf16 (pre-agg h)
  float* asrc    = (float*)(bufA + (size_t)N_NODES * HID);  // N
  float* adst    = asrc + N_NODES;                // N
  float* bnsum   = adst + N_NODES;                // 128
  float* bnsumsq = bnsum + HID;                   // 128
  float* bnscale = bnsumsq + HID;                 // 128
  float* bnshift = bnscale + HID;                 // 128
  float* h4      = bnshift + HID;                 // N*9
  float* bufB    = h4 + (size_t)N_NODES * N_CLS;  // N*128 fp32 (running h)

  const int B256 = 256;
  int gN    = (N_NODES + B256 - 1) / B256;
  int gE    = (N_EDGES + B256 - 1) / B256;
  int gET   = (ETOT + B256 - 1) / B256;
  int gWav  = (N_NODES + 3) / 4;                  // 1 wave/node
  int gMfma = (N_NODES / 16 + 3) / 4;             // 3125 waves -> 782 blocks
  int gBN   = (N_NODES + 127) / 128;
  int gPack = (F_INN * HID + 3 * HID * HID + B256 - 1) / B256;

  // ---- pack weights + CSR ----
  k_pack<<<gPack, B256, 0, stream>>>(W0, Wm, W0T, WmT);
  k_init_deg<<<gN, B256, 0, stream>>>(fill);
  k_count<<<gE, B256, 0, stream>>>(dst, fill);
  k_scan<<<1, 1024, 0, stream>>>(fill, row_ptr);
  k_place<<<gET, B256, 0, stream>>>(src, dst, row_ptr, fill, csr_src);

  // ---- layer 0: h = GAT(x, W0, a0) + b0 -> bufB ----
  k_gemm_mfma<F_INN, false><<<gMfma, B256, 0, stream>>>(x, W0T, nullptr, nullptr,
                                                        a0s, a0d, bufA, asrc, adst);
  k_agg128<<<gWav, B256, 0, stream>>>((const unsigned short*)bufA, asrc, adst, row_ptr,
                                      csr_src, b0, nullptr, nullptr, nullptr, bufB);

  // ---- mid layers: t = leaky(bn(h),0.1) fused into consumers; h = GAT(t) + t ----
  for (int i = 0; i < 3; ++i) {
    k_zero<<<1, 256, 0, stream>>>(bnsum, 2 * HID);
    k_bn_stats<<<gBN, HID, 0, stream>>>(bufB, bnsum, bnsumsq);
    k_bn_final<<<1, HID, 0, stream>>>(bnsum, bnsumsq, gam + i * HID, bet + i * HID,
                                      bnscale, bnshift);
    k_gemm_mfma<HID, true><<<gMfma, B256, 0, stream>>>(bufB, WmT + i * HID * HID,
                                                       bnscale, bnshift,
                                                       ams + i * HID, amd + i * HID,
                                                       bufA, asrc, adst);
    k_agg128<<<gWav, B256, 0, stream>>>((const unsigned short*)bufA, asrc, adst, row_ptr,
                                        csr_src, bm + i * HID, bufB, bnscale, bnshift, bufB);
  }

  // ---- final: t = leaky(bn(h),0.1); out = leaky(GAT(t, W4), 0.1) ----
  k_zero<<<1, 256, 0, stream>>>(bnsum, 2 * HID);
  k_bn_stats<<<gBN, HID, 0, stream>>>(bufB, bnsum, bnsumsq);
  k_bn_final<<<1, HID, 0, stream>>>(bnsum, bnsumsq, gam + 3 * HID, bet + 3 * HID,
                                    bnscale, bnshift);
  k_final_gemm<<<gWav, B256, 0, stream>>>(bufB, bnscale, bnshift, W4, a4s, a4d,
                                          h4, asrc, adst);
  k_final_agg<<<gWav, B256, 0, stream>>>(h4, asrc, adst, row_ptr, csr_src, b4, out);
}

// Round 6
// 1073.268 us; speedup vs baseline: 1.9830x; 1.3239x over previous
//
#include <hip/hip_runtime.h>
#include <hip/hip_bf16.h>

#define N_NODES 50000
#define N_EDGES 800000
#define F_INN   768
#define HID     128
#define N_CLS   9
#define ETOT    (N_EDGES + N_NODES)
#define BN_EPS  1e-5f

typedef __hip_bfloat16 bf16;
typedef __attribute__((ext_vector_type(8))) short bf16x8;
typedef __attribute__((ext_vector_type(4))) float f32x4;

__device__ __forceinline__ float leaky(float v, float s) { return v >= 0.0f ? v : s * v; }
__device__ __forceinline__ int clampn(int s) {
  return ((unsigned)s < (unsigned)N_NODES) ? s : 0;
}
__device__ __forceinline__ short f2bs(float f) {
  bf16 h = __float2bfloat16(f);
  return __builtin_bit_cast(short, h);
}
__device__ __forceinline__ float bs2f(unsigned short u) {
  unsigned v = ((unsigned)u) << 16;
  return __builtin_bit_cast(float, v);
}

// ---------------- pack W0^T, Wm^T to bf16 [n][k] ----------------
__global__ void k_pack(const float* __restrict__ W0, const float* __restrict__ Wm,
                       short* __restrict__ W0T, short* __restrict__ WmT) {
  int i = blockIdx.x * blockDim.x + threadIdx.x;
  if (i < F_INN * HID) {
    int n = i / F_INN, k = i % F_INN;
    W0T[i] = f2bs(W0[k * HID + n]);
  } else if (i < F_INN * HID + 3 * HID * HID) {
    int j = i - F_INN * HID;
    int l = j / (HID * HID), rem = j % (HID * HID);
    int n = rem / HID, k = rem % HID;
    WmT[j] = f2bs(Wm[(l * HID + k) * HID + n]);
  }
}

__global__ void k_zero(float* p, int n) {
  int i = blockIdx.x * blockDim.x + threadIdx.x;
  if (i < n) p[i] = 0.0f;
}

// ---------------- CSR build ----------------
__global__ void k_init_deg(int* fill) {
  int i = blockIdx.x * blockDim.x + threadIdx.x;
  if (i < N_NODES) fill[i] = 1;  // self-loop
}

__global__ void k_count(const int* __restrict__ dst, int* fill) {
  int e = blockIdx.x * blockDim.x + threadIdx.x;
  if (e < N_EDGES) atomicAdd(&fill[clampn(dst[e])], 1);
}

__global__ void k_scan(int* fill, int* row_ptr) {
  __shared__ int sh[1024];
  int tid = threadIdx.x;
  int carry = 0;
  for (int base = 0; base < N_NODES; base += 1024) {
    int i = base + tid;
    int v = (i < N_NODES) ? fill[i] : 0;
    if (i < N_NODES) fill[i] = 0;
    sh[tid] = v;
    __syncthreads();
    for (int off = 1; off < 1024; off <<= 1) {
      int t = (tid >= off) ? sh[tid - off] : 0;
      __syncthreads();
      sh[tid] += t;
      __syncthreads();
    }
    if (i < N_NODES) row_ptr[i] = carry + sh[tid] - v;
    int tot = sh[1023];
    __syncthreads();
    carry += tot;
  }
  if (tid == 0) row_ptr[N_NODES] = carry;
}

__global__ void k_place(const int* __restrict__ src, const int* __restrict__ dst,
                        const int* __restrict__ row_ptr, int* fill, int* csr_src) {
  int id = blockIdx.x * blockDim.x + threadIdx.x;
  if (id >= ETOT) return;
  int s, d;
  if (id < N_EDGES) { s = clampn(src[id]); d = clampn(dst[id]); }
  else { s = id - N_EDGES; d = s; }
  int p = atomicAdd(&fill[d], 1);
  csr_src[row_ptr[d] + p] = s;
}

// ---------------- MFMA GEMM (round-4 verbatim; epilogue fuses attention logits) ----------------
template <int K, bool BN>
__global__ void k_gemm_mfma(const float* __restrict__ X, const short* __restrict__ BT,
                            const float* __restrict__ scale, const float* __restrict__ shift,
                            const float* __restrict__ a_s, const float* __restrict__ a_d,
                            short* __restrict__ hb, float* __restrict__ asrc,
                            float* __restrict__ adst) {
  int wave = (blockIdx.x * blockDim.x + threadIdx.x) >> 6;
  if (wave >= N_NODES / 16) return;
  int lane = threadIdx.x & 63;
  int m = lane & 15, q = lane >> 4;
  int row0 = wave * 16;
  f32x4 acc[8];
#pragma unroll
  for (int t = 0; t < 8; ++t) acc[t] = (f32x4){0.f, 0.f, 0.f, 0.f};
  const float* xrow = X + (size_t)(row0 + m) * K + q * 8;
  const short* brow = BT + (size_t)m * K + q * 8;
  for (int kc = 0; kc < K; kc += 32) {
    float xv[8];
    *(float4*)(xv)     = *(const float4*)(xrow + kc);
    *(float4*)(xv + 4) = *(const float4*)(xrow + kc + 4);
    if (BN) {
      float sc[8], sf[8];
      *(float4*)(sc)     = *(const float4*)(scale + kc + q * 8);
      *(float4*)(sc + 4) = *(const float4*)(scale + kc + q * 8 + 4);
      *(float4*)(sf)     = *(const float4*)(shift + kc + q * 8);
      *(float4*)(sf + 4) = *(const float4*)(shift + kc + q * 8 + 4);
#pragma unroll
      for (int j = 0; j < 8; ++j) xv[j] = leaky(xv[j] * sc[j] + sf[j], 0.1f);
    }
    bf16x8 a;
#pragma unroll
    for (int j = 0; j < 8; ++j) a[j] = f2bs(xv[j]);
#pragma unroll
    for (int t = 0; t < 8; ++t) {
      bf16x8 b = *(const bf16x8*)(brow + kc + (size_t)t * 16 * K);
      acc[t] = __builtin_amdgcn_mfma_f32_16x16x32_bf16(a, b, acc[t], 0, 0, 0);
    }
  }
  float sr[4] = {0.f, 0.f, 0.f, 0.f}, dr[4] = {0.f, 0.f, 0.f, 0.f};
#pragma unroll
  for (int t = 0; t < 8; ++t) {
    float av = a_s[t * 16 + m], dv = a_d[t * 16 + m];
#pragma unroll
    for (int r = 0; r < 4; ++r) {
      float c = acc[t][r];
      hb[(size_t)(row0 + q * 4 + r) * HID + t * 16 + m] = f2bs(c);
      sr[r] += c * av;
      dr[r] += c * dv;
    }
  }
#pragma unroll
  for (int r = 0; r < 4; ++r) {
#pragma unroll
    for (int off = 1; off < 16; off <<= 1) {
      sr[r] += __shfl_xor(sr[r], off);
      dr[r] += __shfl_xor(dr[r], off);
    }
  }
  if (m == 0) {
#pragma unroll
    for (int r = 0; r < 4; ++r) {
      asrc[row0 + q * 4 + r] = sr[r];
      adst[row0 + q * 4 + r] = dr[r];
    }
  }
}

// ---------------- GAT aggregation (H=128): one wave per node ----------------
// Lane-parallel logits (asrc loaded once per edge), max/z via butterfly.
// Gather phase: (ss, ex) staged in per-wave LDS, all lanes read broadcast
// entries (no cross-lane shuffles of masked-lane values).
// hres may alias out (wave reads only its own row before writing it).
__global__ void k_agg128(const unsigned short* __restrict__ h, const float* __restrict__ asrc,
                         const float* __restrict__ adst, const int* __restrict__ row_ptr,
                         const int* __restrict__ csr_src, const float* __restrict__ bias,
                         const float* __restrict__ hres, const float* __restrict__ scale,
                         const float* __restrict__ shift, float* __restrict__ out) {
  __shared__ int   lds_ss[4][64];
  __shared__ float lds_ex[4][64];
  int wid = (blockIdx.x * blockDim.x + threadIdx.x) >> 6;
  int lane = threadIdx.x & 63;
  int w = (threadIdx.x >> 6) & 3;   // wave slot in block
  if (wid >= N_NODES) return;
  int c0 = 2 * lane;
  int beg = row_ptr[wid], end = row_ptr[wid + 1];
  float adsti = adst[wid];
  // pass A: lane-parallel max + butterfly reduce
  float mx = -1e30f;
  for (int cb = beg; cb < end; cb += 64) {
    int e = cb + lane;
    if (e < end) {
      int s = clampn(csr_src[e]);
      mx = fmaxf(mx, leaky(asrc[s] + adsti, 0.2f));
    }
  }
#pragma unroll
  for (int off = 1; off < 64; off <<= 1) mx = fmaxf(mx, __shfl_xor(mx, off));
  // pass B: lane-parallel exp -> LDS stage -> broadcast gather
  float z = 0.f, a0 = 0.f, a1 = 0.f;
  for (int cb = beg; cb < end; cb += 64) {
    int cnt = min(64, end - cb);
    int sl = 0;
    float ex = 0.f;
    if (lane < cnt) {
      sl = clampn(csr_src[cb + lane]);
      ex = __expf(leaky(asrc[sl] + adsti, 0.2f) - mx);
    }
    lds_ss[w][lane] = sl;
    lds_ex[w][lane] = ex;
    __builtin_amdgcn_wave_barrier();   // pin LDS write before reads (wave-private region)
    float zp = ex;
#pragma unroll
    for (int off = 1; off < 64; off <<= 1) zp += __shfl_xor(zp, off);
    z += zp;
    for (int j = 0; j < cnt; ++j) {
      int ss = lds_ss[w][j];
      float exj = lds_ex[w][j];
      unsigned hv = *(const unsigned*)(h + (size_t)ss * HID + c0);
      a0 += exj * bs2f((unsigned short)(hv & 0xffffu));
      a1 += exj * bs2f((unsigned short)(hv >> 16));
    }
    __builtin_amdgcn_wave_barrier();   // keep next chunk's writes after these reads
  }
  float inv = (z > 0.0f) ? 1.0f / z : 0.0f;
  float o0 = a0 * inv + bias[c0];
  float o1 = a1 * inv + bias[c0 + 1];
  if (scale) {
    float2 hr = *(const float2*)(hres + (size_t)wid * HID + c0);
    o0 += leaky(hr.x * scale[c0] + shift[c0], 0.1f);
    o1 += leaky(hr.y * scale[c0 + 1] + shift[c0 + 1], 0.1f);
  }
  float2 o = {o0, o1};
  *(float2*)(out + (size_t)wid * HID + c0) = o;
}

// ---------------- BatchNorm stats (round-4 verbatim) ----------------
__global__ void k_bn_stats(const float* __restrict__ h, float* bnsum, float* bnsumsq) {
  int f = threadIdx.x;  // 128
  int r0 = blockIdx.x * 128;
  int r1 = min(r0 + 128, N_NODES);
  float s = 0.0f, s2 = 0.0f;
  for (int r = r0; r < r1; ++r) {
    float v = h[(size_t)r * HID + f];
    s += v;
    s2 += v * v;
  }
  atomicAdd(&bnsum[f], s);
  atomicAdd(&bnsumsq[f], s2);
}

__global__ void k_bn_final(const float* __restrict__ bnsum, const float* __restrict__ bnsumsq,
                           const float* __restrict__ gamma, const float* __restrict__ beta,
                           float* bnscale, float* bnshift) {
  int f = threadIdx.x;
  float mu = bnsum[f] / (float)N_NODES;
  float var = bnsumsq[f] / (float)N_NODES - mu * mu;
  var = fmaxf(var, 0.0f);
  float rstd = rsqrtf(var + BN_EPS);
  float g = gamma[f];
  bnscale[f] = g * rstd;
  bnshift[f] = beta[f] - mu * g * rstd;
}

// ---------------- final layer GEMM (BN fused) + alpha logits (round-4 verbatim) ----------------
__global__ void k_final_gemm(const float* __restrict__ h, const float* __restrict__ scale,
                             const float* __restrict__ shift, const float* __restrict__ W4,
                             const float* __restrict__ a4s, const float* __restrict__ a4d,
                             float* __restrict__ h4, float* __restrict__ asrc,
                             float* __restrict__ adst) {
  int row = (blockIdx.x * blockDim.x + threadIdx.x) >> 6;
  int lane = threadIdx.x & 63;
  if (row >= N_NODES) return;
  float t0 = leaky(h[(size_t)row * HID + lane] * scale[lane] + shift[lane], 0.1f);
  float t1 = leaky(h[(size_t)row * HID + 64 + lane] * scale[64 + lane] + shift[64 + lane], 0.1f);
  float myv = 0.0f, s = 0.0f, d = 0.0f;
#pragma unroll
  for (int c = 0; c < N_CLS; ++c) {
    float p = t0 * W4[lane * N_CLS + c] + t1 * W4[(lane + 64) * N_CLS + c];
#pragma unroll
    for (int m = 32; m; m >>= 1) p += __shfl_xor(p, m);
    s += p * a4s[c];
    d += p * a4d[c];
    if (lane == c) myv = p;
  }
  if (lane < N_CLS) h4[(size_t)row * N_CLS + lane] = myv;
  if (lane == 0) { asrc[row] = s; adst[row] = d; }
}

// ---------------- final aggregation (C=9) -> fp32 output (round-4 verbatim) ----------------
__global__ void k_final_agg(const float* __restrict__ h4, const float* __restrict__ asrc,
                            const float* __restrict__ adst, const int* __restrict__ row_ptr,
                            const int* __restrict__ csr_src, const float* __restrict__ b4,
                            float* __restrict__ out) {
  int wid = (blockIdx.x * blockDim.x + threadIdx.x) >> 6;
  int lane = threadIdx.x & 63;
  if (wid >= N_NODES) return;
  int beg = row_ptr[wid], end = row_ptr[wid + 1];
  float adsti = adst[wid];
  float mx = -1e30f;
  for (int e = beg; e < end; ++e) {
    int s = clampn(csr_src[e]);
    float v = leaky(asrc[s] + adsti, 0.2f);
    mx = fmaxf(mx, v);
  }
  float z = 0.0f, a = 0.0f;
  for (int e = beg; e < end; ++e) {
    int s = clampn(csr_src[e]);
    float v = leaky(asrc[s] + adsti, 0.2f);
    float ex = __expf(v - mx);
    z += ex;
    if (lane < N_CLS) a += ex * h4[(size_t)s * N_CLS + lane];
  }
  if (lane < N_CLS) {
    float o = (z > 0.0f) ? a / z : 0.0f;
    o = leaky(o + b4[lane], 0.1f);
    out[(size_t)wid * N_CLS + lane] = o;
  }
}

extern "C" void kernel_launch(void* const* d_in, const int* in_sizes, int n_in,
                              void* d_out, int out_size, void* d_ws, size_t ws_size,
                              hipStream_t stream) {
  const float* x   = (const float*)d_in[0];
  const int*   ei  = (const int*)d_in[1];
  const int*   src = ei;
  const int*   dst = ei + N_EDGES;
  const float* W0  = (const float*)d_in[4];
  const float* a0s = (const float*)d_in[5];
  const float* a0d = (const float*)d_in[6];
  const float* b0  = (const float*)d_in[7];
  const float* Wm  = (const float*)d_in[8];
  const float* ams = (const float*)d_in[9];
  const float* amd = (const float*)d_in[10];
  const float* bm  = (const float*)d_in[11];
  const float* W4  = (const float*)d_in[12];
  const float* a4s = (const float*)d_in[13];
  const float* a4d = (const float*)d_in[14];
  const float* b4  = (const float*)d_in[15];
  const float* gam = (const float*)d_in[16];
  const float* bet = (const float*)d_in[17];
  float* out = (float*)d_out;

  // ---- workspace layout (~45 MB), same as round 4 ----
  int* row_ptr   = (int*)d_ws;                    // 50001 (pad 50004)
  int* fill      = row_ptr + 50004;               // N
  int* csr_src   = fill + N_NODES;                // ETOT
  short* W0T     = (short*)(csr_src + ETOT);      // 98304
  short* WmT     = W0T + F_INN * HID;             // 49152
  short* bufA    = WmT + 3 * HID * HID;           // N*128 bf16 (pre-agg h)
  float* asrc    = (float*)(bufA + (size_t)N_NODES * HID);  // N
  float* adst    = asrc + N_NODES;                // N
  float* bnsum   = adst + N_NODES;                // 128
  float* bnsumsq = bnsum + HID;                   // 128
  float* bnscale = bnsumsq + HID;                 // 128
  float* bnshift = bnscale + HID;                 // 128
  float* h4      = bnshift + HID;                 // N*9
  float* bufB    = h4 + (size_t)N_NODES * N_CLS;  // N*128 fp32 (running h)

  const int B256 = 256;
  int gN    = (N_NODES + B256 - 1) / B256;
  int gE    = (N_EDGES + B256 - 1) / B256;
  int gET   = (ETOT + B256 - 1) / B256;
  int gWav  = (N_NODES + 3) / 4;
  int gMfma = (N_NODES / 16 + 3) / 4;
  int gBN   = (N_NODES + 127) / 128;
  int gPack = (F_INN * HID + 3 * HID * HID + B256 - 1) / B256;

  // ---- pack weights + CSR ----
  k_pack<<<gPack, B256, 0, stream>>>(W0, Wm, W0T, WmT);
  k_init_deg<<<gN, B256, 0, stream>>>(fill);
  k_count<<<gE, B256, 0, stream>>>(dst, fill);
  k_scan<<<1, 1024, 0, stream>>>(fill, row_ptr);
  k_place<<<gET, B256, 0, stream>>>(src, dst, row_ptr, fill, csr_src);

  // ---- layer 0: h = GAT(x, W0, a0) + b0 -> bufB ----
  k_gemm_mfma<F_INN, false><<<gMfma, B256, 0, stream>>>(x, W0T, nullptr, nullptr,
                                                        a0s, a0d, bufA, asrc, adst);
  k_agg128<<<gWav, B256, 0, stream>>>((const unsigned short*)bufA, asrc, adst, row_ptr,
                                      csr_src, b0, nullptr, nullptr, nullptr, bufB);

  // ---- mid layers: t = leaky(bn(h),0.1) fused; h = GAT(t) + t ----
  for (int i = 0; i < 3; ++i) {
    k_zero<<<1, 256, 0, stream>>>(bnsum, 2 * HID);
    k_bn_stats<<<gBN, HID, 0, stream>>>(bufB, bnsum, bnsumsq);
    k_bn_final<<<1, HID, 0, stream>>>(bnsum, bnsumsq, gam + i * HID, bet + i * HID,
                                      bnscale, bnshift);
    k_gemm_mfma<HID, true><<<gMfma, B256, 0, stream>>>(bufB, WmT + i * HID * HID,
                                                       bnscale, bnshift,
                                                       ams + i * HID, amd + i * HID,
                                                       bufA, asrc, adst);
    k_agg128<<<gWav, B256, 0, stream>>>((const unsigned short*)bufA, asrc, adst, row_ptr,
                                        csr_src, bm + i * HID, bufB, bnscale, bnshift, bufB);
  }

  // ---- final: t = leaky(bn(h),0.1); out = leaky(GAT(t, W4), 0.1) ----
  k_zero<<<1, 256, 0, stream>>>(bnsum, 2 * HID);
  k_bn_stats<<<gBN, HID, 0, stream>>>(bufB, bnsum, bnsumsq);
  k_bn_final<<<1, HID, 0, stream>>>(bnsum, bnsumsq, gam + 3 * HID, bet + 3 * HID,
                                    bnscale, bnshift);
  k_final_gemm<<<gWav, B256, 0, stream>>>(bufB, bnscale, bnshift, W4, a4s, a4d,
                                          h4, asrc, adst);
  k_final_agg<<<gWav, B256, 0, stream>>>(h4, asrc, adst, row_ptr, csr_src, b4, out);
}